// Round 1
// baseline (405.587 us; speedup 1.0000x reference)
//
#include <hip/hip_runtime.h>

#define T_STEPS 2000
#define NN 39
#define C1N 2496      // 39*64
#define L_CHUNK 125
#define N_CHUNK 16
#define WARM 100

// ---------------- A_hat construction (one tiny block) ----------------
__global__ void build_ahat(const int* __restrict__ edges, float* __restrict__ Ahat) {
    __shared__ float A[NN * NN];
    __shared__ float dinv[NN];
    int tid = threadIdx.x;
    for (int u = tid; u < NN * NN; u += 256) A[u] = 0.0f;
    __syncthreads();
    if (tid < 156) {
        int r = edges[tid];          // edge_index[0][e]
        int c = edges[156 + tid];    // edge_index[1][e]
        atomicAdd(&A[c * NN + r], 1.0f);
    }
    __syncthreads();
    if (tid < NN) {
        float d = 0.0f;
        for (int u = 0; u < NN; ++u) d += A[tid * NN + u];
        dinv[tid] = (d > 0.0f) ? (1.0f / sqrtf(d)) : 0.0f;
    }
    __syncthreads();
    for (int u = tid; u < NN * NN; u += 256) {
        int i = u / NN, j = u % NN;
        Ahat[u] = (dinv[i] * A[u]) * dinv[j];
    }
}

// ---------------- one hop: dst[i,c,t] = sum_m Ahat[i,m] * src[m,c,t] ----------------
// grid (ceil(T/256), 78); blockIdx.y = i*2+c (wave-uniform -> Ahat loads scalarize)
__global__ __launch_bounds__(256) void hop_kernel(const float* __restrict__ src,
                                                  float* __restrict__ dst,
                                                  const float* __restrict__ Ah) {
    int t = blockIdx.x * 256 + threadIdx.x;
    int i = blockIdx.y >> 1, c = blockIdx.y & 1;
    if (t >= T_STEPS) return;
    float acc = 0.0f;
    #pragma unroll
    for (int m = 0; m < NN; ++m)
        acc += Ah[i * NN + m] * src[(m * 2 + c) * T_STEPS + t];
    dst[(i * 2 + c) * T_STEPS + t] = acc;
}

// ---------------- layer-1 scan, conv fused, chunked in time ----------------
// grid (10, N_CHUNK), block 256. Writes u8 spikes FS[t][n].
__global__ __launch_bounds__(256) void scan_c1(const float* __restrict__ X,
    const float* __restrict__ H1, const float* __restrict__ H2, const float* __restrict__ H3,
    const float* __restrict__ Wc, const float* __restrict__ bc,
    unsigned char* __restrict__ FS) {
    int n = blockIdx.x * 256 + threadIdx.x;
    if (n >= C1N) return;
    int i = n >> 6, j = n & 63;
    const float* bases[4] = {X, H1, H2, H3};
    const float* hp[8];
    float wv[8];
    #pragma unroll
    for (int k = 0; k < 4; ++k)
        #pragma unroll
        for (int c = 0; c < 2; ++c) {
            hp[k * 2 + c] = bases[k] + (i * 2 + c) * T_STEPS;
            wv[k * 2 + c] = Wc[(k * 2 + c) * 64 + j];
        }
    float bias = bc[j];
    int t0 = blockIdx.y * L_CHUNK;
    int tw = t0 - WARM; if (tw < 0) tw = 0;
    float m = 0.0f, s = 0.0f;
    for (int t = tw; t < t0; ++t) {
        float acc = 0.0f;
        #pragma unroll
        for (int q = 0; q < 8; ++q) acc += wv[q] * hp[q][t];
        float v = acc + bias;
        m = m * 0.2f * (1.0f - s) + v;
        s = (m > 0.5f) ? 1.0f : 0.0f;
    }
    for (int t = t0; t < t0 + L_CHUNK; ++t) {
        float acc = 0.0f;
        #pragma unroll
        for (int q = 0; q < 8; ++q) acc += wv[q] * hp[q][t];
        float v = acc + bias;
        m = m * 0.2f * (1.0f - s) + v;
        s = (m > 0.5f) ? 1.0f : 0.0f;
        FS[t * C1N + n] = (unsigned char)(s != 0.0f);
    }
}

// ---------------- GEMM1: F1[t][j] += FS[t][:] @ W1[:,j]  (K split 16) ----------------
// grid (32, 16), block 256. F1 must be zeroed beforehand.
__global__ __launch_bounds__(256) void gemm1(const unsigned char* __restrict__ FS,
                                             const float* __restrict__ W1,
                                             float* __restrict__ F1) {
    __shared__ float AT[64 * 64];    // AT[k][t]
    __shared__ float WT[64 * 128];   // WT[k][j]
    int tid = threadIdx.x;
    int t0 = blockIdx.x * 64;
    int kbase = blockIdx.y * 156;
    int jg = (tid & 31) * 4;
    int trow = (tid >> 5) * 8;
    float acc[8][4] = {{0.0f}};
    for (int kk = 0; kk < 156; kk += 64) {
        int kc = 156 - kk; if (kc > 64) kc = 64;
        #pragma unroll
        for (int u = 0; u < 4; ++u) {
            int aid = u * 256 + tid;          // 1024 uchar4 loads
            int t = aid >> 4;
            int k4 = (aid & 15) * 4;
            uchar4 a4 = {0, 0, 0, 0};
            int gt = t0 + t;
            if (k4 < kc && gt < T_STEPS)
                a4 = *(const uchar4*)&FS[gt * C1N + kbase + kk + k4];
            AT[(k4 + 0) * 64 + t] = (float)a4.x;
            AT[(k4 + 1) * 64 + t] = (float)a4.y;
            AT[(k4 + 2) * 64 + t] = (float)a4.z;
            AT[(k4 + 3) * 64 + t] = (float)a4.w;
        }
        #pragma unroll
        for (int u = 0; u < 8; ++u) {
            int fid = u * 256 + tid;          // 2048 float4s
            int k = fid >> 5;
            int j4 = (fid & 31) * 4;
            float4 w = {0.f, 0.f, 0.f, 0.f};
            if (k < kc) w = *(const float4*)&W1[(kbase + kk + k) * 128 + j4];
            *(float4*)&WT[k * 128 + j4] = w;
        }
        __syncthreads();
        #pragma unroll 4
        for (int k = 0; k < 64; ++k) {
            float4 w  = *(const float4*)&WT[k * 128 + jg];
            float4 a0 = *(const float4*)&AT[k * 64 + trow];
            float4 a1 = *(const float4*)&AT[k * 64 + trow + 4];
            float av[8] = {a0.x, a0.y, a0.z, a0.w, a1.x, a1.y, a1.z, a1.w};
            #pragma unroll
            for (int tt = 0; tt < 8; ++tt) {
                acc[tt][0] += av[tt] * w.x;
                acc[tt][1] += av[tt] * w.y;
                acc[tt][2] += av[tt] * w.z;
                acc[tt][3] += av[tt] * w.w;
            }
        }
        __syncthreads();
    }
    #pragma unroll
    for (int tt = 0; tt < 8; ++tt) {
        int gt = t0 + trow + tt;
        if (gt < T_STEPS) {
            atomicAdd(&F1[gt * 128 + jg + 0], acc[tt][0]);
            atomicAdd(&F1[gt * 128 + jg + 1], acc[tt][1]);
            atomicAdd(&F1[gt * 128 + jg + 2], acc[tt][2]);
            atomicAdd(&F1[gt * 128 + jg + 3], acc[tt][3]);
        }
    }
}

// ---------------- h1 scan (128 neurons), chunked ----------------
__global__ void scan_h1(const float* __restrict__ F1, const float* __restrict__ b1,
                        unsigned char* __restrict__ S1) {
    int n = threadIdx.x;   // 128
    int t0 = blockIdx.x * L_CHUNK;
    int tw = t0 - WARM; if (tw < 0) tw = 0;
    float b = b1[n];
    float m = 0.0f, s = 0.0f;
    for (int t = tw; t < t0; ++t) {
        float v = F1[t * 128 + n] + b;
        m = m * 0.2f * (1.0f - s) + v;
        s = (m > 0.5f) ? 1.0f : 0.0f;
    }
    for (int t = t0; t < t0 + L_CHUNK; ++t) {
        float v = F1[t * 128 + n] + b;
        m = m * 0.2f * (1.0f - s) + v;
        s = (m > 0.5f) ? 1.0f : 0.0f;
        S1[t * 128 + n] = (unsigned char)(s != 0.0f);
    }
}

// ---------------- GEMM2: G2[t][j] = S1[t][:] @ W2[:,j]  (K=128) ----------------
// grid 125, block 256 (one j per thread, 16 t per block)
__global__ __launch_bounds__(256) void gemm2(const unsigned char* __restrict__ S1,
                                             const float* __restrict__ W2,
                                             float* __restrict__ G2) {
    __shared__ float AT[128 * 16];   // AT[k][t]
    int tid = threadIdx.x;
    int t0 = blockIdx.x * 16;
    {
        int t = tid >> 4, k0 = (tid & 15) * 8;
        const uchar4* p = (const uchar4*)&S1[(t0 + t) * 128 + k0];
        uchar4 b0 = p[0], b1v = p[1];
        AT[(k0 + 0) * 16 + t] = (float)b0.x;
        AT[(k0 + 1) * 16 + t] = (float)b0.y;
        AT[(k0 + 2) * 16 + t] = (float)b0.z;
        AT[(k0 + 3) * 16 + t] = (float)b0.w;
        AT[(k0 + 4) * 16 + t] = (float)b1v.x;
        AT[(k0 + 5) * 16 + t] = (float)b1v.y;
        AT[(k0 + 6) * 16 + t] = (float)b1v.z;
        AT[(k0 + 7) * 16 + t] = (float)b1v.w;
    }
    __syncthreads();
    int j = tid;
    float acc[16] = {0.0f};
    for (int k = 0; k < 128; ++k) {
        float w = W2[k * 256 + j];
        float4 a0 = *(const float4*)&AT[k * 16 + 0];
        float4 a1 = *(const float4*)&AT[k * 16 + 4];
        float4 a2 = *(const float4*)&AT[k * 16 + 8];
        float4 a3 = *(const float4*)&AT[k * 16 + 12];
        acc[0]  += a0.x * w; acc[1]  += a0.y * w; acc[2]  += a0.z * w; acc[3]  += a0.w * w;
        acc[4]  += a1.x * w; acc[5]  += a1.y * w; acc[6]  += a1.z * w; acc[7]  += a1.w * w;
        acc[8]  += a2.x * w; acc[9]  += a2.y * w; acc[10] += a2.z * w; acc[11] += a2.w * w;
        acc[12] += a3.x * w; acc[13] += a3.y * w; acc[14] += a3.z * w; acc[15] += a3.w * w;
    }
    #pragma unroll
    for (int tt = 0; tt < 16; ++tt) G2[(t0 + tt) * 256 + j] = acc[tt];
}

// ---------------- h2 scan (256 neurons) ----------------
__global__ void scan_h2(const float* __restrict__ G2, const float* __restrict__ b2,
                        unsigned char* __restrict__ S2) {
    int n = threadIdx.x;   // 256
    int t0 = blockIdx.x * L_CHUNK;
    int tw = t0 - WARM; if (tw < 0) tw = 0;
    float b = b2[n];
    float m = 0.0f, s = 0.0f;
    for (int t = tw; t < t0; ++t) {
        float v = G2[t * 256 + n] + b;
        m = m * 0.2f * (1.0f - s) + v;
        s = (m > 0.5f) ? 1.0f : 0.0f;
    }
    for (int t = t0; t < t0 + L_CHUNK; ++t) {
        float v = G2[t * 256 + n] + b;
        m = m * 0.2f * (1.0f - s) + v;
        s = (m > 0.5f) ? 1.0f : 0.0f;
        S2[t * 256 + n] = (unsigned char)(s != 0.0f);
    }
}

// ---------------- GEMM3: G3[t][j] = S2[t][:] @ W3[:,j]  (K=256, N=36) ----------------
// grid 334, block 256 (240 active: j = tid%40, 6 t per block)
__global__ void gemm3(const unsigned char* __restrict__ S2, const float* __restrict__ W3,
                      float* __restrict__ G3) {
    int tid = threadIdx.x;
    int j = tid % 40, dt = tid / 40;
    int t = blockIdx.x * 6 + dt;
    if (j >= 36 || dt >= 6 || t >= T_STEPS) return;
    float acc = 0.0f;
    for (int k = 0; k < 256; ++k) {
        float a = (float)S2[t * 256 + k];
        acc += a * W3[k * 36 + j];
    }
    G3[t * 36 + j] = acc;
}

// ---------------- h3 scan + per-chunk spike counts ----------------
__global__ void scan_h3(const float* __restrict__ G3, const float* __restrict__ b3,
                        float* __restrict__ PART) {
    int n = threadIdx.x;
    if (n >= 36) return;
    int t0 = blockIdx.x * L_CHUNK;
    int tw = t0 - WARM; if (tw < 0) tw = 0;
    float b = b3[n];
    float m = 0.0f, s = 0.0f;
    int cnt = 0;
    for (int t = tw; t < t0; ++t) {
        float v = G3[t * 36 + n] + b;
        m = m * 0.2f * (1.0f - s) + v;
        s = (m > 0.5f) ? 1.0f : 0.0f;
    }
    for (int t = t0; t < t0 + L_CHUNK; ++t) {
        float v = G3[t * 36 + n] + b;
        m = m * 0.2f * (1.0f - s) + v;
        s = (m > 0.5f) ? 1.0f : 0.0f;
        cnt += (s != 0.0f) ? 1 : 0;
    }
    PART[blockIdx.x * 36 + n] = (float)cnt;
}

__global__ void finalize(const float* __restrict__ PART, float* __restrict__ out) {
    int j = threadIdx.x;
    if (j >= 36) return;
    float sum = 0.0f;
    for (int c = 0; c < N_CHUNK; ++c) sum += PART[c * 36 + j];
    out[j] = sum / 2000.0f;
}

extern "C" void kernel_launch(void* const* d_in, const int* in_sizes, int n_in,
                              void* d_out, int out_size, void* d_ws, size_t ws_size,
                              hipStream_t stream) {
    const float* x  = (const float*)d_in[0];
    const int*   ei = (const int*)d_in[1];
    const float* Wc = (const float*)d_in[2];
    const float* bc = (const float*)d_in[3];
    const float* W1 = (const float*)d_in[4];
    const float* b1 = (const float*)d_in[5];
    const float* W2 = (const float*)d_in[6];
    const float* b2 = (const float*)d_in[7];
    const float* W3 = (const float*)d_in[8];
    const float* b3 = (const float*)d_in[9];
    float* out = (float*)d_out;

    // workspace layout (~10.5 MB)
    float* AH  = (float*)d_ws;               // 1536
    float* H1b = AH  + 1536;                 // 156000
    float* H2b = H1b + 156000;
    float* H3b = H2b + 156000;
    float* F1b = H3b + 156000;               // 256000 (zeroed: atomic target)
    float* G2b = F1b + 256000;               // 512000
    float* G3b = G2b + 512000;               // 72000
    float* PB  = G3b + 72000;                // 1024
    unsigned char* FSb = (unsigned char*)(PB + 1024);  // 4,992,000 B
    unsigned char* S1b = FSb + (size_t)T_STEPS * C1N;  // 256,000 B
    unsigned char* S2b = S1b + (size_t)T_STEPS * 128;  // 512,000 B

    build_ahat<<<1, 256, 0, stream>>>(ei, AH);
    hop_kernel<<<dim3(8, 78), 256, 0, stream>>>(x,   H1b, AH);
    hop_kernel<<<dim3(8, 78), 256, 0, stream>>>(H1b, H2b, AH);
    hop_kernel<<<dim3(8, 78), 256, 0, stream>>>(H2b, H3b, AH);
    hipMemsetAsync(F1b, 0, (size_t)T_STEPS * 128 * sizeof(float), stream);
    scan_c1<<<dim3(10, N_CHUNK), 256, 0, stream>>>(x, H1b, H2b, H3b, Wc, bc, FSb);
    gemm1<<<dim3(32, 16), 256, 0, stream>>>(FSb, W1, F1b);
    scan_h1<<<N_CHUNK, 128, 0, stream>>>(F1b, b1, S1b);
    gemm2<<<125, 256, 0, stream>>>(S1b, W2, G2b);
    scan_h2<<<N_CHUNK, 256, 0, stream>>>(G2b, b2, S2b);
    gemm3<<<334, 256, 0, stream>>>(S2b, W3, G3b);
    scan_h3<<<N_CHUNK, 64, 0, stream>>>(G3b, b3, PB);
    finalize<<<1, 64, 0, stream>>>(PB, out);
}

// Round 2
// 263.098 us; speedup vs baseline: 1.5416x; 1.5416x over previous
//
#include <hip/hip_runtime.h>

#define T_STEPS 2000
#define NN 39
#define K1 2496          // 39*64, original K
#define K2 4992          // hi/lo duplicated K
#define KS 6             // K-splits in gemm1 (no atomics; partial buffers)
#define KSP 832          // K2 per split = 13 chunks of 64
#define KCHUNKS 13
#define CH_L 50
#define CH_W 50
#define NCH 40           // 40*50 = 2000

using short8 = __attribute__((ext_vector_type(8))) short;
using floatx4 = __attribute__((ext_vector_type(4))) float;

// ---------------- A_hat construction (one tiny block) ----------------
__global__ void build_ahat(const int* __restrict__ edges, float* __restrict__ Ahat) {
    __shared__ float A[NN * NN];
    __shared__ float dinv[NN];
    int tid = threadIdx.x;
    for (int u = tid; u < NN * NN; u += 256) A[u] = 0.0f;
    __syncthreads();
    if (tid < 156) {
        int r = edges[tid];
        int c = edges[156 + tid];
        atomicAdd(&A[c * NN + r], 1.0f);
    }
    __syncthreads();
    if (tid < NN) {
        float d = 0.0f;
        for (int u = 0; u < NN; ++u) d += A[tid * NN + u];
        dinv[tid] = (d > 0.0f) ? (1.0f / sqrtf(d)) : 0.0f;
    }
    __syncthreads();
    for (int u = tid; u < NN * NN; u += 256) {
        int i = u / NN, j = u % NN;
        Ahat[u] = (dinv[i] * A[u]) * dinv[j];
    }
}

// ---------------- one hop: dst[i,c,t] = sum_m Ahat[i,m] * src[m,c,t] ----------------
__global__ __launch_bounds__(256) void hop_kernel(const float* __restrict__ src,
                                                  float* __restrict__ dst,
                                                  const float* __restrict__ Ah) {
    int t = blockIdx.x * 256 + threadIdx.x;
    int i = blockIdx.y >> 1, c = blockIdx.y & 1;
    if (t >= T_STEPS) return;
    float acc = 0.0f;
    #pragma unroll
    for (int m = 0; m < NN; ++m)
        acc += Ah[i * NN + m] * src[(m * 2 + c) * T_STEPS + t];
    dst[(i * 2 + c) * T_STEPS + t] = acc;
}

// ---------------- W1 -> bf16 hi/lo transposed: Uw[j*2496 + k] = hi | (lo<<16) ----------------
// W1t viewed as bf16[128][4992], row j: [2k]=hi(W1[k][j]), [2k+1]=lo
__global__ __launch_bounds__(256) void prep_w1(const float* __restrict__ W1,
                                               unsigned int* __restrict__ Uw) {
    int k = blockIdx.x * 256 + threadIdx.x;
    int j = blockIdx.y;
    if (k >= K1) return;
    float w = W1[k * 128 + j];
    unsigned int ub = __float_as_uint(w);
    unsigned int hi = (ub + 0x7FFFu + ((ub >> 16) & 1u)) >> 16;   // RNE bf16
    float hf = __uint_as_float(hi << 16);
    float r = w - hf;                                              // exact
    unsigned int ur = __float_as_uint(r);
    unsigned int lo = (ur + 0x7FFFu + ((ur >> 16) & 1u)) >> 16;
    Uw[j * K1 + k] = (hi & 0xFFFFu) | (lo << 16);
}

// ---------------- layer-1 scan, conv fused, chunked in time ----------------
__global__ __launch_bounds__(256) void scan_c1(const float* __restrict__ X,
    const float* __restrict__ H1, const float* __restrict__ H2, const float* __restrict__ H3,
    const float* __restrict__ Wc, const float* __restrict__ bc,
    unsigned char* __restrict__ FS) {
    int n = blockIdx.x * 256 + threadIdx.x;
    if (n >= K1) return;
    int i = n >> 6, j = n & 63;
    const float* bases[4] = {X, H1, H2, H3};
    const float* hp[8];
    float wv[8];
    #pragma unroll
    for (int k = 0; k < 4; ++k)
        #pragma unroll
        for (int c = 0; c < 2; ++c) {
            hp[k * 2 + c] = bases[k] + (i * 2 + c) * T_STEPS;
            wv[k * 2 + c] = Wc[(k * 2 + c) * 64 + j];
        }
    float bias = bc[j];
    int t0 = blockIdx.y * CH_L;
    int tw = t0 - CH_W; if (tw < 0) tw = 0;
    float m = 0.0f, s = 0.0f;
    for (int t = tw; t < t0; ++t) {
        float acc = 0.0f;
        #pragma unroll
        for (int q = 0; q < 8; ++q) acc += wv[q] * hp[q][t];
        float v = acc + bias;
        m = m * 0.2f * (1.0f - s) + v;
        s = (m > 0.5f) ? 1.0f : 0.0f;
    }
    for (int t = t0; t < t0 + CH_L; ++t) {
        float acc = 0.0f;
        #pragma unroll
        for (int q = 0; q < 8; ++q) acc += wv[q] * hp[q][t];
        float v = acc + bias;
        m = m * 0.2f * (1.0f - s) + v;
        s = (m > 0.5f) ? 1.0f : 0.0f;
        FS[t * K1 + n] = (unsigned char)(s != 0.0f);
    }
}

// ---------------- GEMM1 (MFMA bf16 hi/lo): F1p[ks][t][j] = FS[t][:] @ W1 (partial K) ------
// grid (63, KS), block 256 (4 waves). M-tile 32 t, N=128 j, K2-split 832 = 13 x 64.
__global__ __launch_bounds__(256) void gemm1(const unsigned char* __restrict__ FS,
                                             const short* __restrict__ W1t,
                                             float* __restrict__ F1p) {
    __shared__ short As[32 * 72];    // [m][k'] pad +8 bf16
    __shared__ short Ws[128 * 72];   // [j][k'] pad +8 bf16
    int tid = threadIdx.x;
    int t0 = blockIdx.x * 32;
    int ks = blockIdx.y;
    int lane = tid & 63;
    int wv = tid >> 6;
    int j0 = wv * 32;
    int row = lane & 15;
    int quad = lane >> 4;

    floatx4 acc00 = {0.f, 0.f, 0.f, 0.f};
    floatx4 acc01 = acc00, acc10 = acc00, acc11 = acc00;

    int kb_orig = ks * 416;   // original-k base of this split
    int kb2 = ks * KSP;       // k' base

    int sm = tid >> 3;              // A staging: row 0..31
    int sb4 = (tid & 7) * 4;        // byte group 0..28

    for (int c = 0; c < KCHUNKS; ++c) {
        // ---- stage A: 32 rows x 32 spikes -> dup'd bf16 ----
        unsigned int u4 = 0;
        int gt = t0 + sm;
        if (gt < T_STEPS)
            u4 = *(const unsigned int*)&FS[gt * K1 + kb_orig + c * 32 + sb4];
        uint4 dd;
        dd.x = (u4 & 0x000000FFu) ? 0x3F803F80u : 0u;
        dd.y = (u4 & 0x0000FF00u) ? 0x3F803F80u : 0u;
        dd.z = (u4 & 0x00FF0000u) ? 0x3F803F80u : 0u;
        dd.w = (u4 & 0xFF000000u) ? 0x3F803F80u : 0u;
        *(uint4*)&As[sm * 72 + sb4 * 2] = dd;
        // ---- stage W: 128 rows x 64 k' bf16 ----
        #pragma unroll
        for (int u = 0; u < 4; ++u) {
            int aid = u * 256 + tid;
            int jj = aid >> 3;
            int ko = (aid & 7) * 8;
            short8 w = *(const short8*)&W1t[jj * K2 + kb2 + c * 64 + ko];
            *(short8*)&Ws[jj * 72 + ko] = w;
        }
        __syncthreads();
        // ---- 2 MFMA K-steps of 32 ----
        #pragma unroll
        for (int s = 0; s < 2; ++s) {
            int k0 = s * 32 + quad * 8;
            short8 a0 = *(const short8*)&As[row * 72 + k0];
            short8 a1 = *(const short8*)&As[(row + 16) * 72 + k0];
            short8 b0 = *(const short8*)&Ws[(j0 + row) * 72 + k0];
            short8 b1 = *(const short8*)&Ws[(j0 + 16 + row) * 72 + k0];
            acc00 = __builtin_amdgcn_mfma_f32_16x16x32_bf16(a0, b0, acc00, 0, 0, 0);
            acc01 = __builtin_amdgcn_mfma_f32_16x16x32_bf16(a0, b1, acc01, 0, 0, 0);
            acc10 = __builtin_amdgcn_mfma_f32_16x16x32_bf16(a1, b0, acc10, 0, 0, 0);
            acc11 = __builtin_amdgcn_mfma_f32_16x16x32_bf16(a1, b1, acc11, 0, 0, 0);
        }
        __syncthreads();
    }
    // ---- store: C/D layout col=lane&15, row=quad*4+reg ----
    float* out = F1p + (size_t)ks * T_STEPS * 128;
    #pragma unroll
    for (int r = 0; r < 4; ++r) {
        int m0 = quad * 4 + r;
        int t = t0 + m0;
        if (t < T_STEPS) {
            out[t * 128 + j0 + row]      = acc00[r];
            out[t * 128 + j0 + 16 + row] = acc01[r];
        }
        int t2 = t0 + 16 + m0;
        if (t2 < T_STEPS) {
            out[t2 * 128 + j0 + row]      = acc10[r];
            out[t2 * 128 + j0 + 16 + row] = acc11[r];
        }
    }
}

// ---------------- h1 scan (128 neurons), sums KS partials, chunked ----------------
__global__ void scan_h1(const float* __restrict__ F1p, const float* __restrict__ b1,
                        unsigned char* __restrict__ S1) {
    int n = threadIdx.x;   // 128
    int t0 = blockIdx.x * CH_L;
    int tw = t0 - CH_W; if (tw < 0) tw = 0;
    float b = b1[n];
    float m = 0.0f, s = 0.0f;
    const float* p0 = F1p + n;
    for (int t = tw; t < t0; ++t) {
        float v = 0.0f;
        #pragma unroll
        for (int p = 0; p < KS; ++p) v += p0[(size_t)p * T_STEPS * 128 + t * 128];
        v += b;
        m = m * 0.2f * (1.0f - s) + v;
        s = (m > 0.5f) ? 1.0f : 0.0f;
    }
    for (int t = t0; t < t0 + CH_L; ++t) {
        float v = 0.0f;
        #pragma unroll
        for (int p = 0; p < KS; ++p) v += p0[(size_t)p * T_STEPS * 128 + t * 128];
        v += b;
        m = m * 0.2f * (1.0f - s) + v;
        s = (m > 0.5f) ? 1.0f : 0.0f;
        S1[t * 128 + n] = (unsigned char)(s != 0.0f);
    }
}

// ---------------- GEMM2: G2[t][j] = S1[t][:] @ W2[:,j]  (K=128) ----------------
__global__ __launch_bounds__(256) void gemm2(const unsigned char* __restrict__ S1,
                                             const float* __restrict__ W2,
                                             float* __restrict__ G2) {
    __shared__ float AT[128 * 16];   // AT[k][t]
    int tid = threadIdx.x;
    int t0 = blockIdx.x * 16;
    {
        int t = tid >> 4, k0 = (tid & 15) * 8;
        const uchar4* p = (const uchar4*)&S1[(t0 + t) * 128 + k0];
        uchar4 b0 = p[0], b1v = p[1];
        AT[(k0 + 0) * 16 + t] = (float)b0.x;
        AT[(k0 + 1) * 16 + t] = (float)b0.y;
        AT[(k0 + 2) * 16 + t] = (float)b0.z;
        AT[(k0 + 3) * 16 + t] = (float)b0.w;
        AT[(k0 + 4) * 16 + t] = (float)b1v.x;
        AT[(k0 + 5) * 16 + t] = (float)b1v.y;
        AT[(k0 + 6) * 16 + t] = (float)b1v.z;
        AT[(k0 + 7) * 16 + t] = (float)b1v.w;
    }
    __syncthreads();
    int j = tid;
    float acc[16] = {0.0f};
    for (int k = 0; k < 128; ++k) {
        float w = W2[k * 256 + j];
        float4 a0 = *(const float4*)&AT[k * 16 + 0];
        float4 a1 = *(const float4*)&AT[k * 16 + 4];
        float4 a2 = *(const float4*)&AT[k * 16 + 8];
        float4 a3 = *(const float4*)&AT[k * 16 + 12];
        acc[0]  += a0.x * w; acc[1]  += a0.y * w; acc[2]  += a0.z * w; acc[3]  += a0.w * w;
        acc[4]  += a1.x * w; acc[5]  += a1.y * w; acc[6]  += a1.z * w; acc[7]  += a1.w * w;
        acc[8]  += a2.x * w; acc[9]  += a2.y * w; acc[10] += a2.z * w; acc[11] += a2.w * w;
        acc[12] += a3.x * w; acc[13] += a3.y * w; acc[14] += a3.z * w; acc[15] += a3.w * w;
    }
    #pragma unroll
    for (int tt = 0; tt < 16; ++tt) G2[(t0 + tt) * 256 + j] = acc[tt];
}

// ---------------- h2 scan (256 neurons) ----------------
__global__ void scan_h2(const float* __restrict__ G2, const float* __restrict__ b2,
                        unsigned char* __restrict__ S2) {
    int n = threadIdx.x;   // 256
    int t0 = blockIdx.x * CH_L;
    int tw = t0 - CH_W; if (tw < 0) tw = 0;
    float b = b2[n];
    float m = 0.0f, s = 0.0f;
    for (int t = tw; t < t0; ++t) {
        float v = G2[t * 256 + n] + b;
        m = m * 0.2f * (1.0f - s) + v;
        s = (m > 0.5f) ? 1.0f : 0.0f;
    }
    for (int t = t0; t < t0 + CH_L; ++t) {
        float v = G2[t * 256 + n] + b;
        m = m * 0.2f * (1.0f - s) + v;
        s = (m > 0.5f) ? 1.0f : 0.0f;
        S2[t * 256 + n] = (unsigned char)(s != 0.0f);
    }
}

// ---------------- GEMM3: G3[t][j] = S2[t][:] @ W3[:,j]  (K=256, N=36) ----------------
__global__ void gemm3(const unsigned char* __restrict__ S2, const float* __restrict__ W3,
                      float* __restrict__ G3) {
    int tid = threadIdx.x;
    int j = tid % 40, dt = tid / 40;
    int t = blockIdx.x * 6 + dt;
    if (j >= 36 || dt >= 6 || t >= T_STEPS) return;
    float acc = 0.0f;
    for (int k = 0; k < 256; ++k) {
        float a = (float)S2[t * 256 + k];
        acc += a * W3[k * 36 + j];
    }
    G3[t * 36 + j] = acc;
}

// ---------------- h3 scan + per-chunk spike counts ----------------
__global__ void scan_h3(const float* __restrict__ G3, const float* __restrict__ b3,
                        float* __restrict__ PART) {
    int n = threadIdx.x;
    if (n >= 36) return;
    int t0 = blockIdx.x * CH_L;
    int tw = t0 - CH_W; if (tw < 0) tw = 0;
    float b = b3[n];
    float m = 0.0f, s = 0.0f;
    int cnt = 0;
    for (int t = tw; t < t0; ++t) {
        float v = G3[t * 36 + n] + b;
        m = m * 0.2f * (1.0f - s) + v;
        s = (m > 0.5f) ? 1.0f : 0.0f;
    }
    for (int t = t0; t < t0 + CH_L; ++t) {
        float v = G3[t * 36 + n] + b;
        m = m * 0.2f * (1.0f - s) + v;
        s = (m > 0.5f) ? 1.0f : 0.0f;
        cnt += (s != 0.0f) ? 1 : 0;
    }
    PART[blockIdx.x * 36 + n] = (float)cnt;
}

__global__ void finalize(const float* __restrict__ PART, float* __restrict__ out) {
    int j = threadIdx.x;
    if (j >= 36) return;
    float sum = 0.0f;
    for (int c = 0; c < NCH; ++c) sum += PART[c * 36 + j];
    out[j] = sum / 2000.0f;
}

extern "C" void kernel_launch(void* const* d_in, const int* in_sizes, int n_in,
                              void* d_out, int out_size, void* d_ws, size_t ws_size,
                              hipStream_t stream) {
    const float* x  = (const float*)d_in[0];
    const int*   ei = (const int*)d_in[1];
    const float* Wc = (const float*)d_in[2];
    const float* bc = (const float*)d_in[3];
    const float* W1 = (const float*)d_in[4];
    const float* b1 = (const float*)d_in[5];
    const float* W2 = (const float*)d_in[6];
    const float* b2 = (const float*)d_in[7];
    const float* W3 = (const float*)d_in[8];
    const float* b3 = (const float*)d_in[9];
    float* out = (float*)d_out;

    // workspace layout (~17.4 MB)
    float* AH  = (float*)d_ws;                       // 1536
    float* H1b = AH  + 1536;                         // 156000 each
    float* H2b = H1b + 156000;
    float* H3b = H2b + 156000;
    float* F1p = H3b + 156000;                       // KS * 256000 = 1,536,000
    float* G2b = F1p + (size_t)KS * 256000;          // 512000
    float* G3b = G2b + 512000;                       // 72000
    float* PB  = G3b + 72000;                        // 1536
    unsigned short* W1t = (unsigned short*)(PB + 1536);        // 128*4992 shorts
    unsigned char* FSb  = (unsigned char*)(W1t + 128 * K2);    // 2000*2496 B
    unsigned char* S1b  = FSb + (size_t)T_STEPS * K1;
    unsigned char* S2b  = S1b + (size_t)T_STEPS * 128;

    build_ahat<<<1, 256, 0, stream>>>(ei, AH);
    hop_kernel<<<dim3(8, 78), 256, 0, stream>>>(x,   H1b, AH);
    hop_kernel<<<dim3(8, 78), 256, 0, stream>>>(H1b, H2b, AH);
    hop_kernel<<<dim3(8, 78), 256, 0, stream>>>(H2b, H3b, AH);
    prep_w1<<<dim3(10, 128), 256, 0, stream>>>(W1, (unsigned int*)W1t);
    scan_c1<<<dim3(10, NCH), 256, 0, stream>>>(x, H1b, H2b, H3b, Wc, bc, FSb);
    gemm1<<<dim3(63, KS), 256, 0, stream>>>(FSb, (const short*)W1t, F1p);
    scan_h1<<<NCH, 128, 0, stream>>>(F1p, b1, S1b);
    gemm2<<<125, 256, 0, stream>>>(S1b, W2, G2b);
    scan_h2<<<NCH, 256, 0, stream>>>(G2b, b2, S2b);
    gemm3<<<334, 256, 0, stream>>>(S2b, W3, G3b);
    scan_h3<<<NCH, 64, 0, stream>>>(G3b, b3, PB);
    finalize<<<1, 64, 0, stream>>>(PB, out);
}